// Round 2
// baseline (1224.938 us; speedup 1.0000x reference)
//
#include <hip/hip_runtime.h>

// ---------------------------------------------------------------------------
// LSTM_Encoder: emb-concat -> 2-layer BiLSTM (H=200/dir) -> span pack
// B=16, L=128, IN=1218, H=200, 4H=800, LSTM_DIM=400, SMAX=8001
// R1: gx stored as f16; k_rec stages per-step gx slab (25.6 KB) into LDS via
//     async global_load_lds dwordx4 (latency hidden under phase-1 MFMA).
// ---------------------------------------------------------------------------

typedef short s16x8 __attribute__((ext_vector_type(8)));
typedef float f32x4 __attribute__((ext_vector_type(4)));

#define MFMA16(a, b, c) __builtin_amdgcn_mfma_f32_16x16x32_bf16(a, b, c, 0, 0, 0)

__device__ __forceinline__ unsigned short f2b(float f) {
    union { float f; unsigned u; } v; v.f = f;
    unsigned r = v.u + 0x7FFFu + ((v.u >> 16) & 1u);   // RNE
    return (unsigned short)(r >> 16);
}

// ---------------- embedding concat -> bf16 [2048][1248] ---------------------
__global__ __launch_bounds__(256) void k_embed(
    const float* __restrict__ ext, const float* __restrict__ wrd,
    const float* __restrict__ pos, const float* __restrict__ dep,
    const float* __restrict__ ent, const float* __restrict__ iob,
    const float* __restrict__ bert,
    const int* __restrict__ wi, const int* __restrict__ pi,
    const int* __restrict__ di, const int* __restrict__ ei,
    const int* __restrict__ ii, unsigned short* __restrict__ emb)
{
    int r = blockIdx.x;                 // b*128 + l
    int w  = wi[r];
    int wid = (w >= 20000) ? 1 : w;
    int p = pi[r], dd = di[r], e = ei[r], io = ii[r];
    for (int c = threadIdx.x; c < 1248; c += 256) {
        float v;
        if      (c < 300)  v = ext[(size_t)w * 300 + c] + wrd[(size_t)wid * 300 + c];
        else if (c < 350)  v = pos[p * 50 + (c - 300)];
        else if (c < 400)  v = dep[dd * 50 + (c - 350)];
        else if (c < 425)  v = ent[e * 25 + (c - 400)];
        else if (c < 450)  v = iob[io * 25 + (c - 425)];
        else if (c < 1218) v = bert[(size_t)r * 768 + (c - 450)];
        else               v = 0.f;
        emb[(size_t)r * 1248 + c] = f2b(v);
    }
}

// ---------------- weight converts ------------------------------------------
__global__ __launch_bounds__(256) void k_cvt_wih(
    const float* __restrict__ src, unsigned short* __restrict__ dst, int K, int Kp)
{
    int n = blockIdx.x;                 // 0..1599
    for (int c = threadIdx.x; c < Kp; c += 256)
        dst[(size_t)n * Kp + c] = f2b(c < K ? src[(size_t)n * K + c] : 0.f);
}

// whh (2,800,200) fp32 -> packed MFMA-B frags: [d][tile(50)][kf(7)][lane(64)][8]
__global__ __launch_bounds__(64) void k_cvt_whh(
    const float* __restrict__ src, unsigned short* __restrict__ dst)
{
    int blk = blockIdx.x;               // d*350 + t*7 + kf   (700 blocks)
    int kf = blk % 7, t = (blk / 7) % 50, d = blk / 350;
    int lane = threadIdx.x;
    int n = t * 16 + (lane & 15);
    int k0 = kf * 32 + (lane >> 4) * 8;
    for (int j = 0; j < 8; ++j) {
        int k = k0 + j;
        float v = (k < 200) ? src[((size_t)d * 800 + n) * 200 + k] : 0.f;
        dst[(size_t)blk * 512 + lane * 8 + j] = f2b(v);
    }
}

__global__ __launch_bounds__(256) void k_bias(
    const float* __restrict__ bih, const float* __restrict__ bhh, float* __restrict__ out)
{
    int i = blockIdx.x * 256 + threadIdx.x;
    if (i < 1600) out[i] = bih[i] + bhh[i];
}

__global__ __launch_bounds__(64) void k_lens(
    const int* __restrict__ wi, int* __restrict__ lens, float* __restrict__ outTail)
{
    int b = threadIdx.x;
    if (b < 16) {
        int c = 0;
        for (int l = 0; l < 128; ++l) c += (wi[b * 128 + l] != 0);
        lens[b] = c;
        outTail[b] = (float)(c - 2);
    }
}

// ---------------- input-projection GEMM ------------------------------------
// gx[(d*128+l)*16+b][800] (f16) = emb[b*128+l][:] . Wih[d*800+g][:] + bias
__global__ __launch_bounds__(256) void k_gemm(
    const unsigned short* __restrict__ A, const unsigned short* __restrict__ W,
    const float* __restrict__ bias, _Float16* __restrict__ gx, int lda, int nkf)
{
    int wave = (blockIdx.x << 2) | (threadIdx.x >> 6);  // 0..3199
    int lane = threadIdx.x & 63;
    int sm = (wave / 25) * 16;
    int sn = (wave % 25) * 64;
    int l15 = lane & 15, q = lane >> 4;

    const unsigned short* ap = A + (size_t)(sm + l15) * lda + q * 8;
    const unsigned short* wp = W + (size_t)(sn + l15) * lda + q * 8;

    f32x4 acc[4];
    #pragma unroll
    for (int t = 0; t < 4; ++t) acc[t] = 0.f;

    for (int kf = 0; kf < nkf; ++kf) {
        s16x8 a = *(const s16x8*)(ap + kf * 32);
        #pragma unroll
        for (int t = 0; t < 4; ++t) {
            s16x8 b = *(const s16x8*)(wp + (size_t)(t * 16) * lda + kf * 32);
            acc[t] = MFMA16(a, b, acc[t]);
        }
    }
    int m0 = sm + q * 4;
    int bb = m0 >> 7;
    #pragma unroll
    for (int t = 0; t < 4; ++t) {
        int n = sn + t * 16 + l15;
        int d = (n >= 800) ? 1 : 0;
        int rem = n - d * 800;
        float bs = bias[n];
        #pragma unroll
        for (int r = 0; r < 4; ++r) {
            int l = (m0 + r) & 127;
            gx[(size_t)((d * 128 + l) * 16 + bb) * 800 + rem] = (_Float16)(acc[t][r] + bs);
        }
    }
}

// ---------------- recurrence: one WG per direction -------------------------
// 512 threads (8 waves). Whh: 5 tiles/wave in VGPRs + tiles 40..49 in LDS.
// LDS: Bl 71680 | hfr 7168 | g 51328 | gxh 25600  = 155776 B
__global__ __launch_bounds__(512) void k_rec(
    const _Float16* __restrict__ gx,         // [2][128][16][800] f16
    const unsigned short* __restrict__ whhp, // packed [2][50][7][64][8]
    const int* __restrict__ wi,              // [16][128]
    unsigned short* __restrict__ outb, int ldb,  // bf16 [2048][ldb] or null
    float* __restrict__ hf, float* __restrict__ hb) // [16][128][200] or null
{
    extern __shared__ char smem[];
    unsigned short* Bl   = (unsigned short*)smem;            // 35840 bf16
    unsigned short* hfr  = (unsigned short*)(smem + 71680);  // 3584 bf16
    float*          g    = (float*)(smem + 78848);           // 16 x 802 f32
    _Float16*       gxh  = (_Float16*)(smem + 130176);       // 16 x 800 f16

    const int d   = blockIdx.x;
    const int tid = threadIdx.x;
    const int w = tid >> 6, lane = tid & 63;
    const int l15 = lane & 15, q = lane >> 4;

    // stage LDS B tiles 40..49
    {
        const float4* src = (const float4*)(whhp + (size_t)d * 179200 + 143360);
        float4* dst = (float4*)Bl;
        for (int i = tid; i < 4480; i += 512) dst[i] = src[i];
    }
    // zero h frags (incl. k-pad 200..223)
    for (int i = tid; i < 1792; i += 512) ((float*)hfr)[i] = 0.f;

    // resident B tiles: wave w owns tiles w+8i, i=0..4
    s16x8 Bv[5][7];
    #pragma unroll
    for (int i = 0; i < 5; ++i)
        #pragma unroll
        for (int kf = 0; kf < 7; ++kf)
            Bv[i][kf] = *(const s16x8*)(whhp + (size_t)d * 179200 +
                                        (size_t)((w + 8 * i) * 7 + kf) * 512 + lane * 8);

    float c0[4] = {0.f, 0.f, 0.f, 0.f};
    float c1[4] = {0.f, 0.f, 0.f, 0.f};
    const int gb = tid >> 6;   // gate-phase batch base (0..7)
    const int gj = tid & 63;

    __syncthreads();

    for (int t = 0; t < 128; ++t) {
        const int l = d ? (127 - t) : t;

        // async stage this step's gx slab (25600 B = 25 x 1KB wave-chunks)
        {
            const unsigned int* src =
                (const unsigned int*)(gx + (size_t)(d * 128 + l) * 12800);
            for (int c = w; c < 25; c += 8) {
                __builtin_amdgcn_global_load_lds(
                    (const __attribute__((address_space(1))) unsigned int*)(src + c * 256 + lane * 4),
                    (__attribute__((address_space(3))) unsigned int*)(gxh + c * 512),
                    16, 0, 0);
            }
        }
        // hoist mask reads (L1-resident after step 0)
        const bool mt0 = (wi[gb * 128 + l] != 0);
        const bool mt1 = (wi[(gb + 8) * 128 + l] != 0);

        // phase 1: g_hw = h @ Whh^T
        f32x4 acc[7];
        #pragma unroll
        for (int i = 0; i < 7; ++i) acc[i] = 0.f;
        #pragma unroll
        for (int kf = 0; kf < 7; ++kf) {
            s16x8 a = *(const s16x8*)(hfr + kf * 512 + lane * 8);
            #pragma unroll
            for (int i = 0; i < 5; ++i) acc[i] = MFMA16(a, Bv[i][kf], acc[i]);
            s16x8 b5 = *(const s16x8*)(Bl + (size_t)(w * 7 + kf) * 512 + lane * 8);
            acc[5] = MFMA16(a, b5, acc[5]);
            if (w < 2) {
                s16x8 b6 = *(const s16x8*)(Bl + (size_t)((8 + w) * 7 + kf) * 512 + lane * 8);
                acc[6] = MFMA16(a, b6, acc[6]);
            }
        }
        // write g (C-frag: col=l15, row=q*4+r)
        #pragma unroll
        for (int i = 0; i < 5; ++i) {
            int n = (w + 8 * i) * 16 + l15;
            #pragma unroll
            for (int r = 0; r < 4; ++r) g[(q * 4 + r) * 802 + n] = acc[i][r];
        }
        {
            int n = (40 + w) * 16 + l15;
            #pragma unroll
            for (int r = 0; r < 4; ++r) g[(q * 4 + r) * 802 + n] = acc[5][r];
        }
        if (w < 2) {
            int n = (48 + w) * 16 + l15;
            #pragma unroll
            for (int r = 0; r < 4; ++r) g[(q * 4 + r) * 802 + n] = acc[6][r];
        }
        __syncthreads();   // drains global_load_lds (vmcnt) + g/hfr LDS ops

        // phase 2: gates
        #pragma unroll
        for (int bh = 0; bh < 2; ++bh) {
            int b_ = gb + 8 * bh;
            bool mt = bh ? mt1 : mt0;
            float* cc = bh ? c1 : c0;
            #pragma unroll
            for (int ji = 0; ji < 4; ++ji) {
                int j = gj + 64 * ji;
                if (j < 200) {
                    float giv = g[b_ * 802 + j]       + (float)gxh[b_ * 800 + j];
                    float gfv = g[b_ * 802 + 200 + j] + (float)gxh[b_ * 800 + 200 + j];
                    float ggv = g[b_ * 802 + 400 + j] + (float)gxh[b_ * 800 + 400 + j];
                    float gov = g[b_ * 802 + 600 + j] + (float)gxh[b_ * 800 + 600 + j];
                    float si = __builtin_amdgcn_rcpf(1.f + __builtin_amdgcn_exp2f(-1.442695041f * giv));
                    float sf = __builtin_amdgcn_rcpf(1.f + __builtin_amdgcn_exp2f(-1.442695041f * gfv));
                    float so = __builtin_amdgcn_rcpf(1.f + __builtin_amdgcn_exp2f(-1.442695041f * gov));
                    float ag = fabsf(ggv);
                    float eg = __builtin_amdgcn_exp2f(-2.885390082f * ag);
                    float tg = (1.f - eg) * __builtin_amdgcn_rcpf(1.f + eg);
                    tg = copysignf(tg, ggv);
                    float cn = sf * cc[ji] + si * tg;
                    float ac = fabsf(cn);
                    float ec = __builtin_amdgcn_exp2f(-2.885390082f * ac);
                    float tc = (1.f - ec) * __builtin_amdgcn_rcpf(1.f + ec);
                    tc = copysignf(tc, cn);
                    float hn = so * tc;
                    float outv;
                    if (mt) {
                        cc[ji] = cn;
                        int kf = j >> 5, qq = (j >> 3) & 3, jj = j & 7;
                        hfr[kf * 512 + (qq * 16 + b_) * 8 + jj] = f2b(hn);
                        outv = hn;
                    } else {
                        outv = 0.f;
                    }
                    int row = b_ * 128 + l;
                    if (outb) outb[(size_t)row * ldb + d * 200 + j] = f2b(outv);
                    float* fo = d ? hb : hf;
                    if (fo) fo[(size_t)row * 200 + j] = outv;
                }
            }
        }
        __syncthreads();
    }
}

// ---------------- span pack ------------------------------------------------
__global__ __launch_bounds__(128) void k_span(
    const float* __restrict__ hf, const float* __restrict__ hb,
    const int* __restrict__ lens, float* __restrict__ out)
{
    int blk = blockIdx.x;
    int b = blk / 8001, s = blk % 8001;
    int t = threadIdx.x;
    if (t >= 100) return;
    float4* orow = (float4*)(out + (size_t)blk * 400);
    int len = lens[b];
    int M = len - 2;
    int np = M * (M + 1) / 2;
    if (s >= np) {
        float4 z; z.x = z.y = z.z = z.w = 0.f;
        orow[t] = z;
        return;
    }
    float disc = (float)((2 * M + 1) * (2 * M + 1) - 8 * s);
    int i = (int)(((float)(2 * M + 1) - sqrtf(disc)) * 0.5f);
    if (i < 0) i = 0;
    if (i > M - 1) i = M - 1;
    #define PREF(x) ((x) * M - (x) * ((x) - 1) / 2)
    while (i > 0 && PREF(i) > s) --i;
    while (PREF(i + 1) <= s) ++i;
    int j = i + 1 + (s - PREF(i));
    #undef PREF

    if (t < 50) {
        const float4* pj = (const float4*)(hf + (size_t)(b * 128 + j) * 200);
        const float4* pi = (const float4*)(hf + (size_t)(b * 128 + i) * 200);
        float4 aa = pj[t], bb = pi[t], rr;
        rr.x = aa.x - bb.x; rr.y = aa.y - bb.y; rr.z = aa.z - bb.z; rr.w = aa.w - bb.w;
        orow[t] = rr;
    } else {
        int t2 = t - 50;
        const float4* pi = (const float4*)(hb + (size_t)(b * 128 + i + 1) * 200);
        const float4* pj = (const float4*)(hb + (size_t)(b * 128 + j + 1) * 200);
        float4 aa = pi[t2], bb = pj[t2], rr;
        rr.x = aa.x - bb.x; rr.y = aa.y - bb.y; rr.z = aa.z - bb.z; rr.w = aa.w - bb.w;
        orow[t] = rr;
    }
}

// ---------------------------------------------------------------------------
extern "C" void kernel_launch(void* const* d_in, const int* in_sizes, int n_in,
                              void* d_out, int out_size, void* d_ws, size_t ws_size,
                              hipStream_t stream)
{
    const float* ext  = (const float*)d_in[0];
    const float* wrd  = (const float*)d_in[1];
    const float* pos  = (const float*)d_in[2];
    const float* dep  = (const float*)d_in[3];
    const float* ent  = (const float*)d_in[4];
    const float* iob  = (const float*)d_in[5];
    const float* wih0 = (const float*)d_in[6];
    const float* whh0 = (const float*)d_in[7];
    const float* bih0 = (const float*)d_in[8];
    const float* bhh0 = (const float*)d_in[9];
    const float* wih1 = (const float*)d_in[10];
    const float* whh1 = (const float*)d_in[11];
    const float* bih1 = (const float*)d_in[12];
    const float* bhh1 = (const float*)d_in[13];
    const float* bert = (const float*)d_in[14];
    const int* wi = (const int*)d_in[15];
    const int* pi = (const int*)d_in[16];
    const int* di = (const int*)d_in[17];
    const int* ei = (const int*)d_in[18];
    const int* ii = (const int*)d_in[19];
    float* out = (float*)d_out;

    char* ws = (char*)d_ws;
    unsigned short* emb   = (unsigned short*)(ws + 0);         // 5,111,808
    unsigned short* wih0b = (unsigned short*)(ws + 5111808);   // 3,993,600
    unsigned short* wih1b = (unsigned short*)(ws + 9105408);   // 1,331,200
    unsigned short* whh0p = (unsigned short*)(ws + 10436608);  // 716,800
    unsigned short* whh1p = (unsigned short*)(ws + 11153408);  // 716,800
    float*          bias0 = (float*)(ws + 11870208);           // 6,400
    float*          bias1 = (float*)(ws + 11876608);           // 6,400
    int*            lens  = (int*)(ws + 11883008);             // 64
    _Float16*       gx0   = (_Float16*)(ws + 11883072);        // 6,553,600
    _Float16*       gx1   = (_Float16*)(ws + 18436672);        // 6,553,600
    unsigned short* out0b = (unsigned short*)(ws + 24990272);  // 1,703,936
    float*          hfv   = (float*)(ws + 26694208);           // 1,638,400
    float*          hbv   = (float*)(ws + 28332608);           // 1,638,400 (end 29,971,008)

    hipFuncSetAttribute((const void*)k_rec,
                        hipFuncAttributeMaxDynamicSharedMemorySize, 155776);

    k_lens <<<1, 64, 0, stream>>>(wi, lens, out + 51206400);
    k_embed<<<2048, 256, 0, stream>>>(ext, wrd, pos, dep, ent, iob, bert,
                                      wi, pi, di, ei, ii, emb);
    k_cvt_wih<<<1600, 256, 0, stream>>>(wih0, wih0b, 1218, 1248);
    k_cvt_wih<<<1600, 256, 0, stream>>>(wih1, wih1b, 400, 416);
    k_cvt_whh<<<700, 64, 0, stream>>>(whh0, whh0p);
    k_cvt_whh<<<700, 64, 0, stream>>>(whh1, whh1p);
    k_bias<<<7, 256, 0, stream>>>(bih0, bhh0, bias0);
    k_bias<<<7, 256, 0, stream>>>(bih1, bhh1, bias1);
    hipMemsetAsync(out0b, 0, 1703936, stream);   // zero pad cols 400..415

    k_gemm<<<800, 256, 0, stream>>>(emb, wih0b, bias0, gx0, 1248, 39);
    k_rec <<<2, 512, 155776, stream>>>(gx0, whh0p, wi, out0b, 416, nullptr, nullptr);
    k_gemm<<<800, 256, 0, stream>>>(out0b, wih1b, bias1, gx1, 416, 13);
    k_rec <<<2, 512, 155776, stream>>>(gx1, whh1p, wi, nullptr, 0, hfv, hbv);
    k_span<<<16 * 8001, 128, 0, stream>>>(hfv, hbv, lens, out);
}

// Round 3
// 1171.364 us; speedup vs baseline: 1.0457x; 1.0457x over previous
//
#include <hip/hip_runtime.h>

// ---------------------------------------------------------------------------
// LSTM_Encoder: emb-concat -> 2-layer BiLSTM (H=200/dir) -> span pack
// R2: gate-aligned tiling. N padded to 4x208=832 = 52 tiles of 16; each wave
// owns whole t-groups {i,f,g,o} so phase 2 runs on MFMA C-fragments in
// registers (no LDS gate roundtrip). gx stored f16 in C-frag layout and
// prefetched one step ahead as the kf=0 MFMA C operand. Double-buffered h
// fragment LDS -> one barrier/step.
// ---------------------------------------------------------------------------

typedef short    s16x8 __attribute__((ext_vector_type(8)));
typedef float    f32x4 __attribute__((ext_vector_type(4)));
typedef _Float16 f16x4 __attribute__((ext_vector_type(4)));

#define MFMA16(a, b, c) __builtin_amdgcn_mfma_f32_16x16x32_bf16(a, b, c, 0, 0, 0)

__device__ __forceinline__ unsigned short f2b(float f) {
    union { float f; unsigned u; } v; v.f = f;
    unsigned r = v.u + 0x7FFFu + ((v.u >> 16) & 1u);   // RNE
    return (unsigned short)(r >> 16);
}

// ---------------- embedding concat -> bf16 [2048][1248] ---------------------
__global__ __launch_bounds__(256) void k_embed(
    const float* __restrict__ ext, const float* __restrict__ wrd,
    const float* __restrict__ pos, const float* __restrict__ dep,
    const float* __restrict__ ent, const float* __restrict__ iob,
    const float* __restrict__ bert,
    const int* __restrict__ wi, const int* __restrict__ pi,
    const int* __restrict__ di, const int* __restrict__ ei,
    const int* __restrict__ ii, unsigned short* __restrict__ emb)
{
    int r = blockIdx.x;                 // b*128 + l
    int w  = wi[r];
    int wid = (w >= 20000) ? 1 : w;
    int p = pi[r], dd = di[r], e = ei[r], io = ii[r];
    for (int c = threadIdx.x; c < 1248; c += 256) {
        float v;
        if      (c < 300)  v = ext[(size_t)w * 300 + c] + wrd[(size_t)wid * 300 + c];
        else if (c < 350)  v = pos[p * 50 + (c - 300)];
        else if (c < 400)  v = dep[dd * 50 + (c - 350)];
        else if (c < 425)  v = ent[e * 25 + (c - 400)];
        else if (c < 450)  v = iob[io * 25 + (c - 425)];
        else if (c < 1218) v = bert[(size_t)r * 768 + (c - 450)];
        else               v = 0.f;
        emb[(size_t)r * 1248 + c] = f2b(v);
    }
}

// ---------------- weight converts ------------------------------------------
// Wih fp32 [2][800][K] -> bf16 padded [2][832][Kp]; padded row n: g*208+j
__global__ __launch_bounds__(256) void k_cvt_wih(
    const float* __restrict__ src, unsigned short* __restrict__ dst, int K, int Kp)
{
    int n = blockIdx.x;                 // 0..1663
    int dd = n / 832, rem = n % 832, g = rem / 208, j = rem % 208;
    bool v = (j < 200);
    const float* s = src + ((size_t)dd * 800 + g * 200 + j) * K;
    for (int c = threadIdx.x; c < Kp; c += 256)
        dst[(size_t)n * Kp + c] = (v && c < K) ? f2b(s[c]) : (unsigned short)0;
}

// whh (2,800,200) fp32 -> packed MFMA-B frags [d][52][7][512]
// tile = g*13 + tt, tile row l15 -> orig row g*200 + tt*16 + l15
__global__ __launch_bounds__(64) void k_cvt_whh(
    const float* __restrict__ src, unsigned short* __restrict__ dst)
{
    int blk = blockIdx.x;               // d*364 + tile*7 + kf   (728 blocks)
    int kf = blk % 7, tile = (blk / 7) % 52, dd = blk / 364;
    int g = tile / 13, tt = tile % 13;
    int lane = threadIdx.x;
    int l15 = lane & 15, q = lane >> 4;
    int jr = tt * 16 + l15;
    for (int jj = 0; jj < 8; ++jj) {
        int k = kf * 32 + q * 8 + jj;
        float v = (jr < 200 && k < 200)
                ? src[((size_t)dd * 800 + g * 200 + jr) * 200 + k] : 0.f;
        dst[(size_t)blk * 512 + lane * 8 + jj] = f2b(v);
    }
}

// bias padded [2][832]
__global__ __launch_bounds__(256) void k_bias(
    const float* __restrict__ bih, const float* __restrict__ bhh, float* __restrict__ out)
{
    int i = blockIdx.x * 256 + threadIdx.x;
    if (i < 1664) {
        int dd = i / 832, rem = i % 832, g = rem / 208, j = rem % 208;
        out[i] = (j < 200) ? bih[dd * 800 + g * 200 + j] + bhh[dd * 800 + g * 200 + j]
                           : 0.f;
    }
}

__global__ __launch_bounds__(64) void k_lens(
    const int* __restrict__ wi, int* __restrict__ lens, float* __restrict__ outTail)
{
    int b = threadIdx.x;
    if (b < 16) {
        int c = 0;
        for (int l = 0; l < 128; ++l) c += (wi[b * 128 + l] != 0);
        lens[b] = c;
        outTail[b] = (float)(c - 2);
    }
}

// ---------------- input-projection GEMM ------------------------------------
// Output in C-frag layout f16: gxf[(d*128+l)*52 + tile][lane][r]
// wave = (d*128+l)*13 + nstrip; A rows = 16 batches at fixed l (row b*128+l)
__global__ __launch_bounds__(256) void k_gemm(
    const unsigned short* __restrict__ A, const unsigned short* __restrict__ W,
    const float* __restrict__ biasp, _Float16* __restrict__ gxf, int lda, int nkf)
{
    int wave = (blockIdx.x << 2) | (threadIdx.x >> 6);  // 0..3327
    int lane = threadIdx.x & 63;
    int l15 = lane & 15, q = lane >> 4;
    int nstrip = wave % 13;
    int ml = wave / 13;            // d*128 + l
    int l = ml & 127, d = ml >> 7;

    const unsigned short* ap = A + (size_t)(l15 * 128 + l) * lda + q * 8;
    const unsigned short* wp = W + (size_t)(d * 832 + nstrip * 64 + l15) * lda + q * 8;

    f32x4 acc[4];
    #pragma unroll
    for (int t = 0; t < 4; ++t) acc[t] = 0.f;

    for (int kf = 0; kf < nkf; ++kf) {
        s16x8 a = *(const s16x8*)(ap + kf * 32);
        #pragma unroll
        for (int t = 0; t < 4; ++t) {
            s16x8 b = *(const s16x8*)(wp + (size_t)(t * 16) * lda + kf * 32);
            acc[t] = MFMA16(a, b, acc[t]);
        }
    }
    #pragma unroll
    for (int t = 0; t < 4; ++t) {
        float bs = biasp[d * 832 + nstrip * 64 + t * 16 + l15];
        f16x4 v;
        #pragma unroll
        for (int r = 0; r < 4; ++r) v[r] = (_Float16)(acc[t][r] + bs);
        *(f16x4*)(gxf + ((size_t)ml * 52 + nstrip * 4 + t) * 256 + lane * 4) = v;
    }
}

// ---------------- recurrence: one WG per direction -------------------------
// 512 threads (8 waves). Wave w owns t-group t=w (VGPR tiles) and, for w<5,
// t=8+w (LDS tiles). LDS: Bl 20 tiles 143360 | h0/h1 2x7168 | mask 512.
#define PHASE2(ACC, CV, HV, TT)                                                   \
  {                                                                               \
    const int j = (TT) * 16 + l15;                                                \
    const bool jv = (j < 200);                                                    \
    const int kf6 = j >> 5, qq = (j >> 3) & 3, jj = j & 7;                        \
    _Pragma("unroll")                                                             \
    for (int r = 0; r < 4; ++r) {                                                 \
      const int b_ = q * 4 + r;                                                   \
      const bool mt = (mb >> b_) & 1;                                             \
      float gi = ACC[0][r], gf = ACC[1][r], gg = ACC[2][r], go = ACC[3][r];       \
      float si = __builtin_amdgcn_rcpf(1.f + __builtin_amdgcn_exp2f(-1.442695041f * gi)); \
      float sf = __builtin_amdgcn_rcpf(1.f + __builtin_amdgcn_exp2f(-1.442695041f * gf)); \
      float so = __builtin_amdgcn_rcpf(1.f + __builtin_amdgcn_exp2f(-1.442695041f * go)); \
      float ag = fabsf(gg);                                                       \
      float eg = __builtin_amdgcn_exp2f(-2.885390082f * ag);                      \
      float tg = copysignf((1.f - eg) * __builtin_amdgcn_rcpf(1.f + eg), gg);     \
      float cn = sf * CV[r] + si * tg;                                            \
      float ac = fabsf(cn);                                                       \
      float ec = __builtin_amdgcn_exp2f(-2.885390082f * ac);                      \
      float tc = copysignf((1.f - ec) * __builtin_amdgcn_rcpf(1.f + ec), cn);     \
      float hn = so * tc;                                                         \
      CV[r] = mt ? cn : CV[r];                                                    \
      HV[r] = mt ? hn : HV[r];                                                    \
      if (jv) {                                                                   \
        hnxt[kf6 * 512 + (qq * 16 + b_) * 8 + jj] = f2b(HV[r]);                   \
        float ov = mt ? HV[r] : 0.f;                                              \
        if (outb) outb[(size_t)(b_ * 128 + l) * 416 + d * 200 + j] = f2b(ov);     \
        if (hf) (d ? hb : hf)[(size_t)(b_ * 128 + l) * 200 + j] = ov;             \
      }                                                                           \
    }                                                                             \
  }

__global__ __launch_bounds__(512, 2) void k_rec(
    const _Float16* __restrict__ gxf,        // [2][128][52][256] f16 (C-frag)
    const unsigned short* __restrict__ whhp, // [2][52][7][512] bf16
    const int* __restrict__ wi,
    unsigned short* __restrict__ outb,       // bf16 [2048][416] or null
    float* __restrict__ hf, float* __restrict__ hb) // [16][128][200] or null
{
    extern __shared__ char smem[];
    unsigned short* Bl = (unsigned short*)smem;               // 143360 B
    unsigned short* h0 = (unsigned short*)(smem + 143360);    // 7168 B
    unsigned short* h1 = (unsigned short*)(smem + 150528);    // 7168 B
    unsigned*     mskL = (unsigned*)(smem + 157696);          // 512 B

    const int d = blockIdx.x, tid = threadIdx.x;
    const int w = tid >> 6, lane = tid & 63, l15 = lane & 15, q = lane >> 4;
    const unsigned short* Wd = whhp + (size_t)d * 186368;
    const bool two = (w < 5);

    // stage 20 LDS B tiles: slot s=w'*4+g -> tile g*13+8+w'  (8960 float4)
    for (int i = tid; i < 8960; i += 512) {
        int s = i / 448, rr = i % 448;
        int wp = s >> 2, g = s & 3;
        ((float4*)Bl)[i] = ((const float4*)(Wd + (size_t)(g * 13 + 8 + wp) * 3584))[rr];
    }
    // zero both h buffers (3584 dwords)
    for (int i = tid; i < 3584; i += 512) ((unsigned*)h0)[i] = 0u;
    // mask bitfield per l
    if (tid < 128) {
        unsigned m = 0;
        for (int b_ = 0; b_ < 16; ++b_) m |= (wi[b_ * 128 + tid] != 0) ? (1u << b_) : 0u;
        mskL[tid] = m;
    }

    // VGPR B tiles: t-group t=w, gates 0..3
    s16x8 Bv[4][7];
    #pragma unroll
    for (int g = 0; g < 4; ++g)
        #pragma unroll
        for (int kf = 0; kf < 7; ++kf)
            Bv[g][kf] = *(const s16x8*)(Wd + (size_t)(g * 13 + w) * 3584 + kf * 512 + lane * 8);

    float c0[4] = {0,0,0,0}, hh0[4] = {0,0,0,0};
    float c1[4] = {0,0,0,0}, hh1[4] = {0,0,0,0};
    f16x4 gxv0[4], gxv1[4];

    {   // prefetch step 0 gx
        const int l0 = d ? 127 : 0;
        const _Float16* gp = gxf + (size_t)(d * 128 + l0) * 13312 + lane * 4;
        #pragma unroll
        for (int g = 0; g < 4; ++g) gxv0[g] = *(const f16x4*)(gp + (g * 13 + w) * 256);
        if (two) {
            #pragma unroll
            for (int g = 0; g < 4; ++g) gxv1[g] = *(const f16x4*)(gp + (g * 13 + 8 + w) * 256);
        }
    }

    __syncthreads();

    for (int t = 0; t < 128; ++t) {
        const int l = d ? 127 - t : t;
        const unsigned short* hcur = (t & 1) ? h1 : h0;
        unsigned short*       hnxt = (t & 1) ? h0 : h1;

        f32x4 acc0[4], acc1[4];
        {   // kf = 0 : C operand = prefetched gx (cvt f16->f32)
            s16x8 a = *(const s16x8*)(hcur + lane * 8);
            #pragma unroll
            for (int g = 0; g < 4; ++g) {
                f32x4 ci;
                #pragma unroll
                for (int r = 0; r < 4; ++r) ci[r] = (float)gxv0[g][r];
                acc0[g] = MFMA16(a, Bv[g][0], ci);
            }
            if (two) {
                #pragma unroll
                for (int g = 0; g < 4; ++g) {
                    f32x4 ci;
                    #pragma unroll
                    for (int r = 0; r < 4; ++r) ci[r] = (float)gxv1[g][r];
                    s16x8 b = *(const s16x8*)(Bl + (size_t)(w * 4 + g) * 3584 + lane * 8);
                    acc1[g] = MFMA16(a, b, ci);
                }
            }
        }
        // prefetch next step's gx (consumed next iteration; drains at barrier)
        {
            const int tn = (t < 127) ? t + 1 : 127;
            const int ln = d ? 127 - tn : tn;
            const _Float16* gp = gxf + (size_t)(d * 128 + ln) * 13312 + lane * 4;
            #pragma unroll
            for (int g = 0; g < 4; ++g) gxv0[g] = *(const f16x4*)(gp + (g * 13 + w) * 256);
            if (two) {
                #pragma unroll
                for (int g = 0; g < 4; ++g) gxv1[g] = *(const f16x4*)(gp + (g * 13 + 8 + w) * 256);
            }
        }
        #pragma unroll
        for (int kf = 1; kf < 7; ++kf) {
            s16x8 a = *(const s16x8*)(hcur + kf * 512 + lane * 8);
            #pragma unroll
            for (int g = 0; g < 4; ++g) acc0[g] = MFMA16(a, Bv[g][kf], acc0[g]);
            if (two) {
                #pragma unroll
                for (int g = 0; g < 4; ++g) {
                    s16x8 b = *(const s16x8*)(Bl + (size_t)(w * 4 + g) * 3584 + kf * 512 + lane * 8);
                    acc1[g] = MFMA16(a, b, acc1[g]);
                }
            }
        }

        const unsigned mb = mskL[l];
        PHASE2(acc0, c0, hh0, w)
        if (two) PHASE2(acc1, c1, hh1, 8 + w)

        __syncthreads();
    }
}

// ---------------- span pack ------------------------------------------------
__global__ __launch_bounds__(128) void k_span(
    const float* __restrict__ hf, const float* __restrict__ hb,
    const int* __restrict__ lens, float* __restrict__ out)
{
    int blk = blockIdx.x;
    int b = blk / 8001, s = blk % 8001;
    int t = threadIdx.x;
    if (t >= 100) return;
    float4* orow = (float4*)(out + (size_t)blk * 400);
    int len = lens[b];
    int M = len - 2;
    int np = M * (M + 1) / 2;
    if (s >= np) {
        float4 z; z.x = z.y = z.z = z.w = 0.f;
        orow[t] = z;
        return;
    }
    float disc = (float)((2 * M + 1) * (2 * M + 1) - 8 * s);
    int i = (int)(((float)(2 * M + 1) - sqrtf(disc)) * 0.5f);
    if (i < 0) i = 0;
    if (i > M - 1) i = M - 1;
    #define PREF(x) ((x) * M - (x) * ((x) - 1) / 2)
    while (i > 0 && PREF(i) > s) --i;
    while (PREF(i + 1) <= s) ++i;
    int j = i + 1 + (s - PREF(i));
    #undef PREF

    if (t < 50) {
        const float4* pj = (const float4*)(hf + (size_t)(b * 128 + j) * 200);
        const float4* pi = (const float4*)(hf + (size_t)(b * 128 + i) * 200);
        float4 aa = pj[t], bb = pi[t], rr;
        rr.x = aa.x - bb.x; rr.y = aa.y - bb.y; rr.z = aa.z - bb.z; rr.w = aa.w - bb.w;
        orow[t] = rr;
    } else {
        int t2 = t - 50;
        const float4* pi = (const float4*)(hb + (size_t)(b * 128 + i + 1) * 200);
        const float4* pj = (const float4*)(hb + (size_t)(b * 128 + j + 1) * 200);
        float4 aa = pi[t2], bb = pj[t2], rr;
        rr.x = aa.x - bb.x; rr.y = aa.y - bb.y; rr.z = aa.z - bb.z; rr.w = aa.w - bb.w;
        orow[t] = rr;
    }
}

// ---------------------------------------------------------------------------
extern "C" void kernel_launch(void* const* d_in, const int* in_sizes, int n_in,
                              void* d_out, int out_size, void* d_ws, size_t ws_size,
                              hipStream_t stream)
{
    const float* ext  = (const float*)d_in[0];
    const float* wrd  = (const float*)d_in[1];
    const float* pos  = (const float*)d_in[2];
    const float* dep  = (const float*)d_in[3];
    const float* ent  = (const float*)d_in[4];
    const float* iob  = (const float*)d_in[5];
    const float* wih0 = (const float*)d_in[6];
    const float* whh0 = (const float*)d_in[7];
    const float* bih0 = (const float*)d_in[8];
    const float* bhh0 = (const float*)d_in[9];
    const float* wih1 = (const float*)d_in[10];
    const float* whh1 = (const float*)d_in[11];
    const float* bih1 = (const float*)d_in[12];
    const float* bhh1 = (const float*)d_in[13];
    const float* bert = (const float*)d_in[14];
    const int* wi = (const int*)d_in[15];
    const int* pi = (const int*)d_in[16];
    const int* di = (const int*)d_in[17];
    const int* ei = (const int*)d_in[18];
    const int* ii = (const int*)d_in[19];
    float* out = (float*)d_out;

    char* ws = (char*)d_ws;
    unsigned short* emb    = (unsigned short*)(ws + 0);          // 5,111,808
    unsigned short* wih0b  = (unsigned short*)(ws + 5111808);    // 4,153,344
    unsigned short* wih1b  = (unsigned short*)(ws + 9265152);    // 1,384,448
    unsigned short* whh0p  = (unsigned short*)(ws + 10649600);   //   745,472
    unsigned short* whh1p  = (unsigned short*)(ws + 11395072);   //   745,472
    float*          bias0p = (float*)(ws + 12140544);            //     6,656
    float*          bias1p = (float*)(ws + 12147200);            //     6,656
    int*            lens   = (int*)(ws + 12153856);              //        64
    _Float16*       gxf0   = (_Float16*)(ws + 12153920);         // 6,815,744
    _Float16*       gxf1   = (_Float16*)(ws + 18969664);         // 6,815,744
    unsigned short* out0b  = (unsigned short*)(ws + 25785408);   // 1,703,936
    float*          hfv    = (float*)(ws + 27489344);            // 1,638,400
    float*          hbv    = (float*)(ws + 29127744);            // 1,638,400 (end 30,766,144)

    hipFuncSetAttribute((const void*)k_rec,
                        hipFuncAttributeMaxDynamicSharedMemorySize, 158208);

    k_lens <<<1, 64, 0, stream>>>(wi, lens, out + 51206400);
    k_embed<<<2048, 256, 0, stream>>>(ext, wrd, pos, dep, ent, iob, bert,
                                      wi, pi, di, ei, ii, emb);
    k_cvt_wih<<<1664, 256, 0, stream>>>(wih0, wih0b, 1218, 1248);
    k_cvt_wih<<<1664, 256, 0, stream>>>(wih1, wih1b, 400, 416);
    k_cvt_whh<<<728, 64, 0, stream>>>(whh0, whh0p);
    k_cvt_whh<<<728, 64, 0, stream>>>(whh1, whh1p);
    k_bias<<<7, 256, 0, stream>>>(bih0, bhh0, bias0p);
    k_bias<<<7, 256, 0, stream>>>(bih1, bhh1, bias1p);
    hipMemsetAsync(out0b, 0, 1703936, stream);   // zero pad cols 400..415

    k_gemm<<<832, 256, 0, stream>>>(emb, wih0b, bias0p, gxf0, 1248, 39);
    k_rec <<<2, 512, 158208, stream>>>(gxf0, whh0p, wi, out0b, nullptr, nullptr);
    k_gemm<<<832, 256, 0, stream>>>(out0b, wih1b, bias1p, gxf1, 416, 13);
    k_rec <<<2, 512, 158208, stream>>>(gxf1, whh1p, wi, nullptr, hfv, hbv);
    k_span<<<16 * 8001, 128, 0, stream>>>(hfv, hbv, lens, out);
}